// Round 5
// baseline (365.112 us; speedup 1.0000x reference)
//
#include <hip/hip_runtime.h>

#define NN 50000
#define EE 1600000
#define NEG_SLOPE 0.2f

__device__ __forceinline__ void fma4(float4& a, float s, const float4& b) {
  a.x = fmaf(s, b.x, a.x);
  a.y = fmaf(s, b.y, a.y);
  a.z = fmaf(s, b.z, a.z);
  a.w = fmaf(s, b.w, a.w);
}

// ---- P1: feat = h @ W + fused el/er epilogue + fused in-degree histogram ----
// deg and counter are pre-zeroed by hipMemsetAsync before this kernel.
__global__ __launch_bounds__(256) void k_feat(const float* __restrict__ hg,
                                              const float* __restrict__ Wg,
                                              const float* __restrict__ attn_l,
                                              const float* __restrict__ attn_r,
                                              const int* __restrict__ dstg,
                                              float* __restrict__ feat,
                                              float* __restrict__ el,
                                              float* __restrict__ er,
                                              int* __restrict__ deg) {
  __shared__ float sH[64 * 128];   // 32 KB
  __shared__ float sW[128 * 64];   // 32 KB
  int t = threadIdx.x;
  // fused histogram: 782*256 = 200192 threads, ~8 strided passes over E
  for (int i = blockIdx.x * 256 + t; i < EE; i += 782 * 256)
    atomicAdd(&deg[dstg[i]], 1);
  int r0 = blockIdx.x * 64;
  const float4* hg4 = (const float4*)hg;
#pragma unroll
  for (int i = 0; i < 8; i++) {
    int f = t + i * 256;
    int row = f >> 5, kq = f & 31;
    int r = r0 + row;
    float4 v = make_float4(0.f, 0.f, 0.f, 0.f);
    if (r < NN) v = hg4[(size_t)r * 32 + kq];
    *(float4*)&sH[row * 128 + kq * 4] = v;
    ((float4*)sW)[f] = ((const float4*)Wg)[f];
  }
  __syncthreads();
  int tx = t & 15, ty = t >> 4;
  float4 acc[4];
#pragma unroll
  for (int i = 0; i < 4; i++) acc[i] = make_float4(0.f, 0.f, 0.f, 0.f);
  const float4* sW4 = (const float4*)sW;
  for (int k = 0; k < 128; k += 4) {
    float4 w0 = sW4[(k + 0) * 16 + tx];
    float4 w1 = sW4[(k + 1) * 16 + tx];
    float4 w2 = sW4[(k + 2) * 16 + tx];
    float4 w3 = sW4[(k + 3) * 16 + tx];
#pragma unroll
    for (int i = 0; i < 4; i++) {
      float4 hv = *(const float4*)&sH[(ty * 4 + i) * 128 + k];
      fma4(acc[i], hv.x, w0);
      fma4(acc[i], hv.y, w1);
      fma4(acc[i], hv.z, w2);
      fma4(acc[i], hv.w, w3);
    }
  }
  int head = tx >> 2;
  float4 al = ((const float4*)attn_l)[tx];
  float4 ar = ((const float4*)attn_r)[tx];
#pragma unroll
  for (int i = 0; i < 4; i++) {
    int r = r0 + ty * 4 + i;
    float sl = acc[i].x * al.x + acc[i].y * al.y + acc[i].z * al.z + acc[i].w * al.w;
    float sr = acc[i].x * ar.x + acc[i].y * ar.y + acc[i].z * ar.z + acc[i].w * ar.w;
    sl += __shfl_xor(sl, 1); sl += __shfl_xor(sl, 2);
    sr += __shfl_xor(sr, 1); sr += __shfl_xor(sr, 2);
    if (r < NN) {
      ((float4*)feat)[(size_t)r * 16 + tx] = acc[i];
      if ((tx & 3) == 0) {
        el[r * 4 + head] = sl;
        er[r * 4 + head] = sr;
      }
    }
  }
}

// ---- P2: offsets/cursor via wave-prefix + global atomic; block 0 computes c ----
__global__ __launch_bounds__(256) void k_off(const float* __restrict__ We,
                                             const float* __restrict__ ae,
                                             float* __restrict__ c,
                                             const int* __restrict__ deg,
                                             int* __restrict__ offsets,
                                             int* __restrict__ cursor,
                                             int* __restrict__ counter) {
  int t = threadIdx.x;
  if (blockIdx.x == 0) {
    int k = t >> 2, hh = t & 3;
    const float4* we4 = (const float4*)(We + (size_t)k * 64 + hh * 16);
    const float4* ae4 = (const float4*)(ae + hh * 16);
    float s = 0.f;
#pragma unroll
    for (int i = 0; i < 4; i++) {
      float4 v = we4[i];
      float4 a = ae4[i];
      s += v.x * a.x + v.y * a.y + v.z * a.z + v.w * a.w;
    }
    c[k * 4 + hh] = s;
  }
  int n = blockIdx.x * 256 + t;
  int lane = t & 63;
  int d = (n < NN) ? deg[n] : 0;
  int x = d;
#pragma unroll
  for (int dd = 1; dd < 64; dd <<= 1) {
    int y = __shfl_up(x, dd);
    if (lane >= dd) x += y;
  }
  int total = __shfl(x, 63);
  int base = 0;
  if (lane == 63) base = atomicAdd(counter, total);
  base = __shfl(base, 63);
  int offv = base + x - d;
  if (n < NN) {
    offsets[n] = offv;
    cursor[n] = offv;
  }
}

// ---- P3: edge pass — stream ef, compute p=exp(leakyrelu(logit)), scatter
//          (p x4 heads, src) into dst-ordered CSR slots. 4 lanes/edge. ----
__global__ __launch_bounds__(256) void k_edge(const float* __restrict__ ef,
                                              const int* __restrict__ srcg,
                                              const int* __restrict__ dstg,
                                              const float* __restrict__ c,
                                              const float* __restrict__ el,
                                              const float* __restrict__ er,
                                              int* __restrict__ cursor,
                                              int* __restrict__ csr_src,
                                              float* __restrict__ csr_p) {
  __shared__ float4 sc[64];
  int t = threadIdx.x;
  if (t < 64) sc[t] = ((const float4*)c)[t];
  __syncthreads();
  int lane = t & 63;
  int j = t & 3;                      // k-quarter AND head lane
  int e = blockIdx.x * 64 + (t >> 2); // EE % 64 == 0 -> no guard
  const float4* ef4 = (const float4*)(ef + (size_t)e * 64 + j * 16);
  float4 v0 = ef4[0], v1 = ef4[1], v2 = ef4[2], v3 = ef4[3];
  float4 acc = make_float4(0.f, 0.f, 0.f, 0.f);
  int kb = j * 16;
  fma4(acc, v0.x, sc[kb + 0]);  fma4(acc, v0.y, sc[kb + 1]);
  fma4(acc, v0.z, sc[kb + 2]);  fma4(acc, v0.w, sc[kb + 3]);
  fma4(acc, v1.x, sc[kb + 4]);  fma4(acc, v1.y, sc[kb + 5]);
  fma4(acc, v1.z, sc[kb + 6]);  fma4(acc, v1.w, sc[kb + 7]);
  fma4(acc, v2.x, sc[kb + 8]);  fma4(acc, v2.y, sc[kb + 9]);
  fma4(acc, v2.z, sc[kb + 10]); fma4(acc, v2.w, sc[kb + 11]);
  fma4(acc, v3.x, sc[kb + 12]); fma4(acc, v3.y, sc[kb + 13]);
  fma4(acc, v3.z, sc[kb + 14]); fma4(acc, v3.w, sc[kb + 15]);
#pragma unroll
  for (int m = 1; m < 4; m <<= 1) {
    acc.x += __shfl_xor(acc.x, m);
    acc.y += __shfl_xor(acc.y, m);
    acc.z += __shfl_xor(acc.z, m);
    acc.w += __shfl_xor(acc.w, m);
  }
  float eeh = (j == 0) ? acc.x : (j == 1) ? acc.y : (j == 2) ? acc.z : acc.w;
  int es = srcg[e];
  int ed = dstg[e];
  float lg = el[es * 4 + j] + er[ed * 4 + j] + eeh;
  float lv = (lg > 0.f) ? lg : NEG_SLOPE * lg;
  int slot = 0;
  if (j == 0) slot = atomicAdd(&cursor[ed], 1);
  slot = __shfl(slot, lane & ~3);
  if (j == 0) csr_src[slot] = es;
  csr_p[(size_t)slot * 4 + j] = __expf(lv);   // 16B scatter, write side
}

// ---- P4: aggregation + softmax-normalize + ELU ----
// 256-thread blocks, 4 waves = 4 nodes per block; no LDS, no barriers.
// Payload reads are COALESCED streams of the dst-ordered CSR; only the
// feat rows are gathered (256B coalesced per edge, L2/L3-resident table).
__global__ __launch_bounds__(256) void k_aggr(const int* __restrict__ offsets,
                                              const int* __restrict__ deg,
                                              const int* __restrict__ csr_src,
                                              const float* __restrict__ csr_p,
                                              const float* __restrict__ feat,
                                              float* __restrict__ out) {
  int t = threadIdx.x;
  int w = t >> 6, lane = t & 63;
  int n = blockIdx.x * 4 + w;
  if (n >= NN) return;
  int off = offsets[n];
  int dg = deg[n];
  int hh = lane >> 4;          // head of this lane's output column
  int sub = lane >> 2;         // staging: edge slot 0..15
  int comp = lane & 3;         // staging: head component
  float facc = 0.f, dacc = 0.f;
  for (int b = 0; b < dg; b += 16) {
    int i = b + sub;
    float p_l = 0.f;
    int sr_l = 0;
    if (i < dg) {
      p_l = csr_p[(size_t)(off + i) * 4 + comp];   // coalesced 256B stream
      sr_l = csr_src[off + i];                     // coalesced
    }
    dacc += p_l;
    int qcnt = min(16, dg - b);
#pragma unroll 4
    for (int q = 0; q < qcnt; q++) {
      float ph = __shfl(p_l, q * 4 + hh);
      int sq = __shfl(sr_l, q * 4);
      facc = fmaf(ph, feat[(size_t)sq * 64 + lane], facc);
    }
  }
  // denominator: sum over the 16 staging slots (lane bits 2..5), per head comp
#pragma unroll
  for (int m = 4; m < 64; m <<= 1) dacc += __shfl_xor(dacc, m);
  float denom = __shfl(dacc, hh);            // lane hh holds head hh's total
  float r = facc / fmaxf(denom, 1e-16f);
  out[(size_t)n * 64 + lane] = (r > 0.f) ? r : expm1f(r);
}

extern "C" void kernel_launch(void* const* d_in, const int* in_sizes, int n_in,
                              void* d_out, int out_size, void* d_ws, size_t ws_size,
                              hipStream_t stream) {
  const float* h       = (const float*)d_in[0];
  const float* edge_ft = (const float*)d_in[1];
  const int*   src     = (const int*)d_in[2];
  const int*   dst     = (const int*)d_in[3];
  const float* W       = (const float*)d_in[4];
  const float* We      = (const float*)d_in[5];
  const float* attn_l  = (const float*)d_in[6];
  const float* attn_r  = (const float*)d_in[7];
  const float* attn_e  = (const float*)d_in[8];
  float* out = (float*)d_out;

  char* ws = (char*)d_ws;
  float* feat    = (float*)ws;                    // N*64 f32 = 12,800,000 B
  float* el      = feat + (size_t)NN * 64;        // N*4      =    800,000 B
  float* er      = el + NN * 4;                   //               800,000 B
  float* c       = er + NN * 4;                   // 256 f32  =      1,024 B
  int*   deg     = (int*)(c + 256);               // N        =    200,000 B
  int*   counter = deg + NN;                      //                     4 B
  int*   offsets = counter + 1;                   //               200,000 B
  int*   cursor  = offsets + NN;                  //               200,000 B
  int*   csr_src = cursor + NN;                   // E        =  6,400,000 B
  float* csr_p   = (float*)(csr_src + EE);        // E*4 f32  = 25,600,000 B
  if (ws_size < (size_t)48000000) return;

  hipMemsetAsync(deg, 0, (NN + 1) * sizeof(int), stream);  // deg + counter
  k_feat<<<(NN + 63) / 64, 256, 0, stream>>>(h, W, attn_l, attn_r, dst,
                                             feat, el, er, deg);
  k_off<<<(NN + 255) / 256, 256, 0, stream>>>(We, attn_e, c, deg,
                                              offsets, cursor, counter);
  k_edge<<<EE / 64, 256, 0, stream>>>(edge_ft, src, dst, c, el, er,
                                      cursor, csr_src, csr_p);
  k_aggr<<<(NN + 3) / 4, 256, 0, stream>>>(offsets, deg, csr_src, csr_p,
                                           feat, out);
}

// Round 6
// 311.839 us; speedup vs baseline: 1.1708x; 1.1708x over previous
//
#include <hip/hip_runtime.h>

#define NN 50000
#define EE 1600000
#define NEG_SLOPE 0.2f

__device__ __forceinline__ void fma4(float4& a, float s, const float4& b) {
  a.x = fmaf(s, b.x, a.x);
  a.y = fmaf(s, b.y, a.y);
  a.z = fmaf(s, b.z, a.z);
  a.w = fmaf(s, b.w, a.w);
}

// ---- P1: feat = h @ W + fused el/er epilogue; zeroes deg/counter inline ----
__global__ __launch_bounds__(256) void k_feat(const float* __restrict__ hg,
                                              const float* __restrict__ Wg,
                                              const float* __restrict__ attn_l,
                                              const float* __restrict__ attn_r,
                                              float* __restrict__ feat,
                                              float* __restrict__ el,
                                              float* __restrict__ er,
                                              int* __restrict__ deg,
                                              int* __restrict__ counter) {
  __shared__ float sH[64 * 128];   // 32 KB
  __shared__ float sW[128 * 64];   // 32 KB
  int t = threadIdx.x;
  int tid = blockIdx.x * 256 + t;
  if (tid < NN) deg[tid] = 0;      // grid 782*256 = 200192 >= NN
  if (tid == 0) *counter = 0;
  int r0 = blockIdx.x * 64;
  const float4* hg4 = (const float4*)hg;
#pragma unroll
  for (int i = 0; i < 8; i++) {
    int f = t + i * 256;
    int row = f >> 5, kq = f & 31;
    int r = r0 + row;
    float4 v = make_float4(0.f, 0.f, 0.f, 0.f);
    if (r < NN) v = hg4[(size_t)r * 32 + kq];
    *(float4*)&sH[row * 128 + kq * 4] = v;
    ((float4*)sW)[f] = ((const float4*)Wg)[f];
  }
  __syncthreads();
  int tx = t & 15, ty = t >> 4;
  float4 acc[4];
#pragma unroll
  for (int i = 0; i < 4; i++) acc[i] = make_float4(0.f, 0.f, 0.f, 0.f);
  const float4* sW4 = (const float4*)sW;
  for (int k = 0; k < 128; k += 4) {
    float4 w0 = sW4[(k + 0) * 16 + tx];
    float4 w1 = sW4[(k + 1) * 16 + tx];
    float4 w2 = sW4[(k + 2) * 16 + tx];
    float4 w3 = sW4[(k + 3) * 16 + tx];
#pragma unroll
    for (int i = 0; i < 4; i++) {
      float4 hv = *(const float4*)&sH[(ty * 4 + i) * 128 + k];
      fma4(acc[i], hv.x, w0);
      fma4(acc[i], hv.y, w1);
      fma4(acc[i], hv.z, w2);
      fma4(acc[i], hv.w, w3);
    }
  }
  int head = tx >> 2;
  float4 al = ((const float4*)attn_l)[tx];
  float4 ar = ((const float4*)attn_r)[tx];
#pragma unroll
  for (int i = 0; i < 4; i++) {
    int r = r0 + ty * 4 + i;
    float sl = acc[i].x * al.x + acc[i].y * al.y + acc[i].z * al.z + acc[i].w * al.w;
    float sr = acc[i].x * ar.x + acc[i].y * ar.y + acc[i].z * ar.z + acc[i].w * ar.w;
    sl += __shfl_xor(sl, 1); sl += __shfl_xor(sl, 2);
    sr += __shfl_xor(sr, 1); sr += __shfl_xor(sr, 2);
    if (r < NN) {
      ((float4*)feat)[(size_t)r * 16 + tx] = acc[i];
      if ((tx & 3) == 0) {
        el[r * 4 + head] = sl;
        er[r * 4 + head] = sr;
      }
    }
  }
}

// ---- P0: in-degree histogram (separate, streams across all CUs) ----
__global__ __launch_bounds__(256) void k_hist(const int* __restrict__ dstg,
                                              int* __restrict__ deg) {
  int e = blockIdx.x * 256 + threadIdx.x;
  if (e < EE) atomicAdd(&deg[dstg[e]], 1);
}

// ---- P2: offsets/cursor via wave-prefix + global atomic; block 0 computes c ----
__global__ __launch_bounds__(256) void k_off(const float* __restrict__ We,
                                             const float* __restrict__ ae,
                                             float* __restrict__ c,
                                             const int* __restrict__ deg,
                                             int* __restrict__ offsets,
                                             int* __restrict__ cursor,
                                             int* __restrict__ counter) {
  int t = threadIdx.x;
  if (blockIdx.x == 0) {
    int k = t >> 2, hh = t & 3;
    const float4* we4 = (const float4*)(We + (size_t)k * 64 + hh * 16);
    const float4* ae4 = (const float4*)(ae + hh * 16);
    float s = 0.f;
#pragma unroll
    for (int i = 0; i < 4; i++) {
      float4 v = we4[i];
      float4 a = ae4[i];
      s += v.x * a.x + v.y * a.y + v.z * a.z + v.w * a.w;
    }
    c[k * 4 + hh] = s;
  }
  int n = blockIdx.x * 256 + t;
  int lane = t & 63;
  int d = (n < NN) ? deg[n] : 0;
  int x = d;
#pragma unroll
  for (int dd = 1; dd < 64; dd <<= 1) {
    int y = __shfl_up(x, dd);
    if (lane >= dd) x += y;
  }
  int total = __shfl(x, 63);
  int base = 0;
  if (lane == 63) base = atomicAdd(counter, total);
  base = __shfl(base, 63);
  int offv = base + x - d;
  if (n < NN) {
    offsets[n] = offv;
    cursor[n] = offv;
  }
}

// ---- P3: edge pass — stream ef, p = exp(leakyrelu(logit)) scattered into
//          dst-ordered CSR slots (write side). 4 lanes/edge. ----
__global__ __launch_bounds__(256) void k_edge(const float* __restrict__ ef,
                                              const int* __restrict__ srcg,
                                              const int* __restrict__ dstg,
                                              const float* __restrict__ c,
                                              const float* __restrict__ el,
                                              const float* __restrict__ er,
                                              int* __restrict__ cursor,
                                              int* __restrict__ csr_src,
                                              float* __restrict__ csr_p) {
  __shared__ float4 sc[64];
  int t = threadIdx.x;
  if (t < 64) sc[t] = ((const float4*)c)[t];
  __syncthreads();
  int lane = t & 63;
  int j = t & 3;                      // k-quarter AND head lane
  int e = blockIdx.x * 64 + (t >> 2); // EE % 64 == 0 -> no guard
  const float4* ef4 = (const float4*)(ef + (size_t)e * 64 + j * 16);
  float4 v0 = ef4[0], v1 = ef4[1], v2 = ef4[2], v3 = ef4[3];
  float4 acc = make_float4(0.f, 0.f, 0.f, 0.f);
  int kb = j * 16;
  fma4(acc, v0.x, sc[kb + 0]);  fma4(acc, v0.y, sc[kb + 1]);
  fma4(acc, v0.z, sc[kb + 2]);  fma4(acc, v0.w, sc[kb + 3]);
  fma4(acc, v1.x, sc[kb + 4]);  fma4(acc, v1.y, sc[kb + 5]);
  fma4(acc, v1.z, sc[kb + 6]);  fma4(acc, v1.w, sc[kb + 7]);
  fma4(acc, v2.x, sc[kb + 8]);  fma4(acc, v2.y, sc[kb + 9]);
  fma4(acc, v2.z, sc[kb + 10]); fma4(acc, v2.w, sc[kb + 11]);
  fma4(acc, v3.x, sc[kb + 12]); fma4(acc, v3.y, sc[kb + 13]);
  fma4(acc, v3.z, sc[kb + 14]); fma4(acc, v3.w, sc[kb + 15]);
#pragma unroll
  for (int m = 1; m < 4; m <<= 1) {
    acc.x += __shfl_xor(acc.x, m);
    acc.y += __shfl_xor(acc.y, m);
    acc.z += __shfl_xor(acc.z, m);
    acc.w += __shfl_xor(acc.w, m);
  }
  float eeh = (j == 0) ? acc.x : (j == 1) ? acc.y : (j == 2) ? acc.z : acc.w;
  int es = srcg[e];
  int ed = dstg[e];
  float lg = el[es * 4 + j] + er[ed * 4 + j] + eeh;
  float lv = (lg > 0.f) ? lg : NEG_SLOPE * lg;
  int slot = 0;
  if (j == 0) slot = atomicAdd(&cursor[ed], 1);
  slot = __shfl(slot, lane & ~3);
  if (j == 0) csr_src[slot] = es;
  csr_p[(size_t)slot * 4 + j] = __expf(lv);
}

// ---- P4: aggregation + normalize + ELU — latency-parallel version ----
// 256-thr blocks = 4 independent waves = 4 nodes; per-wave-private LDS
// staging (no block barriers). Within a wave: 4 edge-groups x 16 lanes;
// each lane owns 4 output columns (float4). 4 concurrent edges x unroll 4
// = up to 16 feat-row loads in flight per wave.
__global__ __launch_bounds__(256) void k_aggr(const int* __restrict__ offsets,
                                              const int* __restrict__ deg,
                                              const int* __restrict__ csr_src,
                                              const float* __restrict__ csr_p,
                                              const float* __restrict__ feat,
                                              float* __restrict__ out) {
  __shared__ float sp[4][64][4];
  __shared__ int ssrc[4][64];
  int t = threadIdx.x;
  int w = t >> 6, lane = t & 63;
  int n = blockIdx.x * 4 + w;
  if (n >= NN) return;
  int off = offsets[n], dg = deg[n];
  int g = lane >> 4;        // edge subgroup 0..3
  int c = lane & 15;        // column quad: cols 4c..4c+3
  int hd = c >> 2;          // head of these 4 columns
  float4 acc = make_float4(0.f, 0.f, 0.f, 0.f);
  float4 dacc = make_float4(0.f, 0.f, 0.f, 0.f);
  const float4* cp4 = (const float4*)csr_p;
  const float4* f4 = (const float4*)feat;
  for (int b = 0; b < dg; b += 64) {
    int cnt = min(64, dg - b);
    if (lane < cnt) {
      float4 p4 = cp4[off + b + lane];        // coalesced 1KB/wave
      ssrc[w][lane] = csr_src[off + b + lane];
      *(float4*)&sp[w][lane][0] = p4;
      dacc.x += p4.x; dacc.y += p4.y; dacc.z += p4.z; dacc.w += p4.w;
    }
    __builtin_amdgcn_wave_barrier();  // per-wave DS ops are in-order; fence compiler
    int qmax = (cnt - g + 3) >> 2;    // edges e = q*4+g, e < cnt
#pragma unroll 4
    for (int q = 0; q < qmax; q++) {
      int e = q * 4 + g;
      int sq = ssrc[w][e];
      float pe = sp[w][e][hd];
      float4 fv = f4[(size_t)sq * 16 + c];    // 256B/group, 4 groups parallel
      acc.x = fmaf(pe, fv.x, acc.x);
      acc.y = fmaf(pe, fv.y, acc.y);
      acc.z = fmaf(pe, fv.z, acc.z);
      acc.w = fmaf(pe, fv.w, acc.w);
    }
    __builtin_amdgcn_wave_barrier();
  }
  // reduce acc across edge-groups (lane bits 4,5)
#pragma unroll
  for (int m = 16; m < 64; m <<= 1) {
    acc.x += __shfl_xor(acc.x, m);
    acc.y += __shfl_xor(acc.y, m);
    acc.z += __shfl_xor(acc.z, m);
    acc.w += __shfl_xor(acc.w, m);
  }
  // reduce denominators across all 64 lanes
#pragma unroll
  for (int m = 1; m < 64; m <<= 1) {
    dacc.x += __shfl_xor(dacc.x, m);
    dacc.y += __shfl_xor(dacc.y, m);
    dacc.z += __shfl_xor(dacc.z, m);
    dacc.w += __shfl_xor(dacc.w, m);
  }
  float denom = (hd == 0) ? dacc.x : (hd == 1) ? dacc.y : (hd == 2) ? dacc.z : dacc.w;
  float inv = 1.f / fmaxf(denom, 1e-16f);
  acc.x *= inv; acc.y *= inv; acc.z *= inv; acc.w *= inv;
  acc.x = (acc.x > 0.f) ? acc.x : expm1f(acc.x);
  acc.y = (acc.y > 0.f) ? acc.y : expm1f(acc.y);
  acc.z = (acc.z > 0.f) ? acc.z : expm1f(acc.z);
  acc.w = (acc.w > 0.f) ? acc.w : expm1f(acc.w);
  if (g == 0) ((float4*)out)[(size_t)n * 16 + c] = acc;
}

extern "C" void kernel_launch(void* const* d_in, const int* in_sizes, int n_in,
                              void* d_out, int out_size, void* d_ws, size_t ws_size,
                              hipStream_t stream) {
  const float* h       = (const float*)d_in[0];
  const float* edge_ft = (const float*)d_in[1];
  const int*   src     = (const int*)d_in[2];
  const int*   dst     = (const int*)d_in[3];
  const float* W       = (const float*)d_in[4];
  const float* We      = (const float*)d_in[5];
  const float* attn_l  = (const float*)d_in[6];
  const float* attn_r  = (const float*)d_in[7];
  const float* attn_e  = (const float*)d_in[8];
  float* out = (float*)d_out;

  // workspace layout — csr_p kept 16B-aligned (read as float4)
  char* ws = (char*)d_ws;
  float* feat    = (float*)ws;                    // N*64 f32 = 12,800,000 B
  float* el      = feat + (size_t)NN * 64;        //               800,000 B
  float* er      = el + NN * 4;                   //               800,000 B
  float* c       = er + NN * 4;                   //                 1,024 B
  int*   deg     = (int*)(c + 256);               //               200,000 B
  int*   offsets = deg + NN;                      //               200,000 B
  int*   cursor  = offsets + NN;                  //               200,000 B
  int*   csr_src = cursor + NN;                   //             6,400,000 B
  float* csr_p   = (float*)(csr_src + EE);        // 16B-aligned; 25,600,000 B
  int*   counter = (int*)(csr_p + (size_t)EE * 4);//                     4 B
  if (ws_size < (size_t)47001028) return;

  k_feat<<<(NN + 63) / 64, 256, 0, stream>>>(h, W, attn_l, attn_r,
                                             feat, el, er, deg, counter);
  k_hist<<<(EE + 255) / 256, 256, 0, stream>>>(dst, deg);
  k_off<<<(NN + 255) / 256, 256, 0, stream>>>(We, attn_e, c, deg,
                                              offsets, cursor, counter);
  k_edge<<<EE / 64, 256, 0, stream>>>(edge_ft, src, dst, c, el, er,
                                      cursor, csr_src, csr_p);
  k_aggr<<<(NN + 3) / 4, 256, 0, stream>>>(offsets, deg, csr_src, csr_p,
                                           feat, out);
}